// Round 1
// baseline (19505.763 us; speedup 1.0000x reference)
//
#include <hip/hip_runtime.h>
#include <stdint.h>

// ---------------- problem constants ----------------
#define S_LEN 512
#define B_SZ  64
#define E_DIM 512
#define HD    1024
#define NGATE 3072   // 3*HD (r,z,c)
#define O_DIM 10

typedef __attribute__((ext_vector_type(4))) float f32x4;
typedef __attribute__((ext_vector_type(8))) short bf16x8;   // 8 bf16 in 4 VGPRs (guide §3)

__device__ __forceinline__ float bf2f(unsigned short u) {
  union { unsigned int i; float f; } c; c.i = ((unsigned int)u) << 16; return c.f;
}
__device__ __forceinline__ unsigned short f2bf(float f) {   // RNE
  union { float f; unsigned int i; } c; c.f = f;
  unsigned int u = c.i;
  return (unsigned short)((u + 0x7fffu + ((u >> 16) & 1u)) >> 16);
}
__device__ __forceinline__ float sigmoid_fast(float x) { return 1.0f / (1.0f + __expf(-x)); }
__device__ __forceinline__ float tanh_fast(float x) {
  float a = fabsf(x);
  float e = __expf(2.0f * a);            // overflow -> inf -> 2/(inf+1)=0 -> +-1, safe
  return copysignf(1.0f - 2.0f / (e + 1.0f), x);
}
__device__ __forceinline__ f32x4 mfma16(bf16x8 a, bf16x8 b, f32x4 c) {
  return __builtin_amdgcn_mfma_f32_16x16x32_bf16(a, b, c, 0, 0, 0);
}

// ---------------- ws layout (bytes) ----------------
// [Hbf 2x64x1024 bf16 | Hf 64x1024 f32 | slots 4x64 u32 | zscr | pscr | rh | Wr | Wz | Wc | Wx | Xp]
#define OFF_HBF   0
#define OFF_HF    262144
#define OFF_SLOTS 524288
#define OFF_ZSCR  525312
#define OFF_PSCR  787456
#define OFF_RH    1573888
#define OFF_WR    1704960
#define OFF_WZ    3802112
#define OFF_WC    5899264
#define OFF_WX    7996416
#define OFF_XP    11142144
// total ~212.5 MB

// ============================================================================
// convert: fp32 weights -> bf16, pre-swizzled into MFMA B-fragment order.
// B-frag for 16x16x32: lane=(q*16+n) holds B[k0+8q+i][n], i=0..7 -> store
// [jt][kt][lane][8] so B-frag load is a dense 16B/lane read.
// ============================================================================
__global__ void convert_kernel(const float* __restrict__ Whr, const float* __restrict__ Whz,
                               const float* __restrict__ Whc,
                               const float* __restrict__ Wxr, const float* __restrict__ Wxz,
                               const float* __restrict__ Wxc,
                               unsigned short* __restrict__ Wr_swz, unsigned short* __restrict__ Wz_swz,
                               unsigned short* __restrict__ Wc_swz, unsigned short* __restrict__ Wx_swz) {
  long idx = (long)blockIdx.x * blockDim.x + threadIdx.x;
  const long NH = (long)HD * HD;           // 2^20
  if (idx < 3 * NH) {
    int m = (int)(idx >> 20);
    int t = (int)(idx & (NH - 1));
    int k = t >> 10, j = t & 1023;
    const float* src = (m == 0) ? Whr : (m == 1) ? Whz : Whc;
    unsigned short* dst = (m == 0) ? Wr_swz : (m == 1) ? Wz_swz : Wc_swz;
    int jt = j >> 4, n = j & 15, kt = k >> 5, q = (k >> 3) & 3, i = k & 7;
    dst[((long)(jt * 32 + kt) * 64 + (q * 16 + n)) * 8 + i] = f2bf(src[(long)k * HD + j]);
  } else {
    long t = idx - 3 * NH;
    if (t < (long)E_DIM * NGATE) {
      int e  = (int)(t / NGATE);
      int jg = (int)(t - (long)e * NGATE);
      int gate = jg >> 10, jj = jg & 1023;
      const float* src = (gate == 0) ? Wxr : (gate == 1) ? Wxz : Wxc;
      int jt = jg >> 4, n = jg & 15, kt = e >> 5, q = (e >> 3) & 3, i = e & 7;
      Wx_swz[((long)(jt * 16 + kt) * 64 + (q * 16 + n)) * 8 + i] = f2bf(src[(long)e * HD + jj]);
    }
  }
}

// ============================================================================
// embed + X-projection: Xp[s][jglob][b] (bf16, bias folded in)
// block = (slab of 64 j, one s); 4 waves = 4 j-tiles; iterate 4 b-tiles.
// Emb rows staged in LDS bf16 with XOR-16B swizzle (conflict-free A-frags).
// ============================================================================
__launch_bounds__(256, 2)
__global__ void embed_kernel(const int* __restrict__ tokens,      // [B][S]
                             const float* __restrict__ Emb,       // [V][E]
                             const unsigned short* __restrict__ Wx_swz,
                             const float* __restrict__ b_r, const float* __restrict__ b_z,
                             const float* __restrict__ b_c,
                             unsigned short* __restrict__ Xp) {
  __shared__ unsigned short xl[B_SZ * E_DIM];   // 64 KB
  const int s = blockIdx.y;
  const int slab = blockIdx.x;                  // 0..47
  const int tid = threadIdx.x;
  // ---- stage embeddings: 64 rows x 128 float4 ----
  for (int it = 0; it < 32; ++it) {
    int task = tid + 256 * it;
    int row = task >> 7;
    int f = task & 127;
    int tok = tokens[row * S_LEN + s];
    float4 v = *(const float4*)(Emb + (long)tok * E_DIM + f * 4);
    int sw = (f >> 1) ^ (row & 7);              // 16B-chunk XOR swizzle
    unsigned short* p = xl + row * E_DIM + sw * 8 + (f & 1) * 4;
    p[0] = f2bf(v.x); p[1] = f2bf(v.y); p[2] = f2bf(v.z); p[3] = f2bf(v.w);
  }
  __syncthreads();
  const int lane = tid & 63, wave = tid >> 6;
  const int n = lane & 15, q = lane >> 4;
  const int jt_glob = slab * 4 + wave;          // 0..191
  f32x4 acc[4];
  #pragma unroll
  for (int bt = 0; bt < 4; ++bt) { acc[bt][0]=0.f; acc[bt][1]=0.f; acc[bt][2]=0.f; acc[bt][3]=0.f; }
  for (int kt = 0; kt < 16; ++kt) {
    bf16x8 bfrag = *(const bf16x8*)(Wx_swz + ((long)(jt_glob * 16 + kt) * 64 + lane) * 8);
    #pragma unroll
    for (int bt = 0; bt < 4; ++bt) {
      int row = bt * 16 + n;                    // A-frag: m = lane&15
      int chunk = (kt * 4 + q) ^ (row & 7);
      bf16x8 afrag = *(const bf16x8*)(xl + row * E_DIM + chunk * 8);
      acc[bt] = mfma16(afrag, bfrag, acc[bt]);
    }
  }
  const int jglob = jt_glob * 16 + n;
  const int gate = jglob >> 10, jj = jglob & 1023;
  const float bias = (gate == 0 ? b_r : gate == 1 ? b_z : b_c)[jj];
  #pragma unroll
  for (int bt = 0; bt < 4; ++bt) {              // D: col=n(j), rows=16bt+4q+r
    unsigned int lo = (unsigned)f2bf(acc[bt][0] + bias) | ((unsigned)f2bf(acc[bt][1] + bias) << 16);
    unsigned int hi = (unsigned)f2bf(acc[bt][2] + bias) | ((unsigned)f2bf(acc[bt][3] + bias) << 16);
    uint2 pk; pk.x = lo; pk.y = hi;
    *(uint2*)(Xp + ((long)s * NGATE + jglob) * B_SZ + bt * 16 + q * 4) = pk;
  }
}

// ============================================================================
// persistent GRU: 256 blocks (1/CU, all resident), 4 batch-groups x 64 blocks.
// Block owns 16 j-indices. Per step: phase1 (r,z tiles, K-split-2 over wave
// pairs) -> group barrier -> phase2 (c tile, K-split-4) + H update -> barrier.
// W_r/W_z resident in LDS (64KB, frag order); W_c streamed from local L2.
// ============================================================================
__device__ __forceinline__ void group_barrier(unsigned int* slot_base, int bh,
                                              unsigned int seq, int tid, int lane, int wave) {
  __syncthreads();                              // drains each wave's stores (vmcnt)
  if (tid == 0) {
    __threadfence();                            // release: L2 writeback for cross-XCD readers
    __hip_atomic_store(slot_base + bh, seq, __ATOMIC_RELEASE, __HIP_MEMORY_SCOPE_AGENT);
  }
  if (wave == 0) {                              // 64 lanes poll 64 slots, no atomic-RMW contention
    unsigned int v;
    do {
      v = __hip_atomic_load(slot_base + lane, __ATOMIC_RELAXED, __HIP_MEMORY_SCOPE_AGENT);
      if (v >= seq) break;
      __builtin_amdgcn_s_sleep(2);
    } while (true);
    __threadfence();                            // acquire: invalidate stale L1/L2 lines
  }
  __syncthreads();
}

__launch_bounds__(256, 1)
__global__ void gru_kernel(const unsigned short* __restrict__ Xp,
                           const unsigned short* __restrict__ Wr_swz,
                           const unsigned short* __restrict__ Wz_swz,
                           const unsigned short* __restrict__ Wc_swz,
                           unsigned short* __restrict__ Hbf,    // [2][64][1024] bf16
                           float* __restrict__ Hf,              // [64][1024] fp32 master
                           unsigned short* __restrict__ rh,     // [64][1024] bf16 (r*H)
                           float* __restrict__ zscr,            // [256][64][4]
                           float* __restrict__ pscr,            // [256][3][64][4]
                           unsigned int* __restrict__ slots) {  // [4][64]
  __shared__ unsigned short wrz[2 * 32 * 64 * 8];               // 64 KB
  const int tid = threadIdx.x;
  const int lane = tid & 63, wave = tid >> 6;
  const int n = lane & 15, q = lane >> 4;
  const int blk = blockIdx.x;
  const int g  = blk & 3;                       // batch group (rows 16g..16g+15)
  const int bh = blk >> 2;                      // j-tile owner, j in [16bh,16bh+16)
  const int jmine = bh * 16 + n;

  { // one-time: W_r, W_z slices -> LDS (already in frag order, linear copy)
    const uint4* s0 = (const uint4*)(Wr_swz + (long)bh * (32 * 64 * 8));
    const uint4* s1 = (const uint4*)(Wz_swz + (long)bh * (32 * 64 * 8));
    uint4* d0 = (uint4*)wrz;
    uint4* d1 = (uint4*)(wrz + 32 * 64 * 8);
    for (int i = tid; i < 2048; i += 256) { d0[i] = s0[i]; d1[i] = s1[i]; }
  }
  __syncthreads();
  const unsigned short* WcB = Wc_swz + (long)bh * (32 * 64 * 8);
  unsigned int* slot_base = slots + g * 64;

  int cur = 0;
  unsigned int seq = 1;
  f32x4 hold; hold[0]=0.f; hold[1]=0.f; hold[2]=0.f; hold[3]=0.f;  // wave0: fp32 H carried across steps

  for (int s = 0; s < S_LEN; ++s) {
    // ---------------- phase 1: r (waves 0,2) and z (waves 1,3) ----------------
    const int tile  = wave & 1;
    const int khalf = wave >> 1;
    const unsigned short* Hb = Hbf + (long)cur * (B_SZ * HD);
    uint2 xp_pref; xp_pref.x = 0; xp_pref.y = 0;
    if (wave < 2)   // prefetch Xp (HBM) early
      xp_pref = *(const uint2*)(Xp + ((long)s * NGATE + wave * HD + jmine) * B_SZ + g * 16 + q * 4);

    f32x4 acc; acc[0]=0.f; acc[1]=0.f; acc[2]=0.f; acc[3]=0.f;
    {
      const unsigned short* wbase = wrz + tile * (32 * 64 * 8) + lane * 8;
      const unsigned short* abase = Hb + (long)(g * 16 + n) * HD + q * 8;
      #pragma unroll
      for (int t = 0; t < 16; ++t) {
        int kt = khalf * 16 + t;
        bf16x8 af = *(const bf16x8*)(abase + kt * 32);
        bf16x8 bf_ = *(const bf16x8*)(wbase + (long)kt * (64 * 8));
        acc = mfma16(af, bf_, acc);
      }
    }
    if (wave >= 2) *(f32x4*)(pscr + ((long)blk * 3 + (wave - 2)) * 256 + lane * 4) = acc;
    __syncthreads();
    if (wave < 2) {
      const float* pp = pscr + ((long)blk * 3 + wave) * 256 + lane * 4;  // partner partial (same CU -> plain)
      #pragma unroll
      for (int i = 0; i < 4; ++i) acc[i] += pp[i];
      #pragma unroll
      for (int r_ = 0; r_ < 4; ++r_) {
        float xpv = bf2f((unsigned short)(((r_ < 2) ? xp_pref.x : xp_pref.y) >> ((r_ & 1) * 16)));
        float v = sigmoid_fast(acc[r_] + xpv);
        long off = (long)(g * 16 + q * 4 + r_) * HD + jmine;
        if (wave == 0) rh[off] = f2bf(v * hold[r_]);     // r*H (fp32 H)
        else           zscr[(long)blk * 256 + lane * 4 + r_] = v;
      }
    }
    group_barrier(slot_base, bh, seq, tid, lane, wave); seq++;

    // ---------------- phase 2: c tile, K-split-4 ----------------
    uint2 xpc; xpc.x = 0; xpc.y = 0;
    if (wave == 0)
      xpc = *(const uint2*)(Xp + ((long)s * NGATE + 2 * HD + jmine) * B_SZ + g * 16 + q * 4);
    f32x4 acc2; acc2[0]=0.f; acc2[1]=0.f; acc2[2]=0.f; acc2[3]=0.f;
    {
      const unsigned short* abase = rh + (long)(g * 16 + n) * HD + q * 8;
      #pragma unroll
      for (int t = 0; t < 8; ++t) {
        int kt = wave * 8 + t;
        bf16x8 af = *(const bf16x8*)(abase + kt * 32);
        bf16x8 bf_ = *(const bf16x8*)(WcB + (long)kt * (64 * 8) + lane * 8);
        acc2 = mfma16(af, bf_, acc2);
      }
    }
    if (wave >= 1) *(f32x4*)(pscr + ((long)blk * 3 + (wave - 1)) * 256 + lane * 4) = acc2;
    __syncthreads();
    if (wave == 0) {
      #pragma unroll
      for (int p = 0; p < 3; ++p) {
        const float* pp = pscr + ((long)blk * 3 + p) * 256 + lane * 4;
        #pragma unroll
        for (int i = 0; i < 4; ++i) acc2[i] += pp[i];
      }
      unsigned short* Hbn = Hbf + (long)(cur ^ 1) * (B_SZ * HD);
      #pragma unroll
      for (int r_ = 0; r_ < 4; ++r_) {
        float xpv = bf2f((unsigned short)(((r_ < 2) ? xpc.x : xpc.y) >> ((r_ & 1) * 16)));
        float c = tanh_fast(acc2[r_] + xpv);
        float z = zscr[(long)blk * 256 + lane * 4 + r_];
        float hn = z * hold[r_] + (1.0f - z) * c;
        hold[r_] = hn;                                   // carry fp32 H in registers
        long off = (long)(g * 16 + q * 4 + r_) * HD + jmine;
        Hf[off] = hn;
        Hbn[off] = f2bf(hn);
      }
    }
    group_barrier(slot_base, bh, seq, tid, lane, wave); seq++;
    cur ^= 1;
  }
}

// ============================================================================
// logits + softmax: one wave per batch row
// ============================================================================
__global__ void logits_kernel(const float* __restrict__ Hf, const float* __restrict__ Whq,
                              const float* __restrict__ bq, float* __restrict__ out) {
  const int b = blockIdx.x;
  const int lane = threadIdx.x;   // 64
  float acc[O_DIM];
  #pragma unroll
  for (int o = 0; o < O_DIM; ++o) acc[o] = 0.f;
  for (int k = lane; k < HD; k += 64) {
    float h = Hf[(long)b * HD + k];
    #pragma unroll
    for (int o = 0; o < O_DIM; ++o) acc[o] += h * Whq[(long)k * O_DIM + o];
  }
  #pragma unroll
  for (int o = 0; o < O_DIM; ++o) {
    #pragma unroll
    for (int off = 32; off > 0; off >>= 1) acc[o] += __shfl_down(acc[o], off, 64);
  }
  if (lane == 0) {
    float lg[O_DIM], m = -1e30f, sum = 0.f;
    #pragma unroll
    for (int o = 0; o < O_DIM; ++o) { lg[o] = acc[o] + bq[o]; m = fmaxf(m, lg[o]); }
    #pragma unroll
    for (int o = 0; o < O_DIM; ++o) { lg[o] = __expf(lg[o] - m); sum += lg[o]; }
    float inv = 1.0f / sum;
    #pragma unroll
    for (int o = 0; o < O_DIM; ++o) out[(long)b * O_DIM + o] = lg[o] * inv;
  }
}

// ============================================================================
extern "C" void kernel_launch(void* const* d_in, const int* in_sizes, int n_in,
                              void* d_out, int out_size, void* d_ws, size_t ws_size,
                              hipStream_t stream) {
  const int*   tokens = (const int*)d_in[0];
  const float* Emb = (const float*)d_in[1];
  const float* Wxr = (const float*)d_in[2];
  const float* Whr = (const float*)d_in[3];
  const float* br  = (const float*)d_in[4];
  const float* Wxz = (const float*)d_in[5];
  const float* Whz = (const float*)d_in[6];
  const float* bz  = (const float*)d_in[7];
  const float* Wxc = (const float*)d_in[8];
  const float* Whc = (const float*)d_in[9];
  const float* bc  = (const float*)d_in[10];
  const float* Whq = (const float*)d_in[11];
  const float* bq  = (const float*)d_in[12];

  char* ws = (char*)d_ws;
  unsigned short* Hbf    = (unsigned short*)(ws + OFF_HBF);
  float*          Hf     = (float*)(ws + OFF_HF);
  unsigned int*   slots  = (unsigned int*)(ws + OFF_SLOTS);
  float*          zscr   = (float*)(ws + OFF_ZSCR);
  float*          pscr   = (float*)(ws + OFF_PSCR);
  unsigned short* rh     = (unsigned short*)(ws + OFF_RH);
  unsigned short* Wr_swz = (unsigned short*)(ws + OFF_WR);
  unsigned short* Wz_swz = (unsigned short*)(ws + OFF_WZ);
  unsigned short* Wc_swz = (unsigned short*)(ws + OFF_WC);
  unsigned short* Wx_swz = (unsigned short*)(ws + OFF_WX);
  unsigned short* Xp     = (unsigned short*)(ws + OFF_XP);

  // zero H (H0=0), bf16 H buffers, and barrier slots (ws is re-poisoned each call)
  hipMemsetAsync(ws, 0, OFF_ZSCR, stream);

  convert_kernel<<<18432, 256, 0, stream>>>(Whr, Whz, Whc, Wxr, Wxz, Wxc,
                                            Wr_swz, Wz_swz, Wc_swz, Wx_swz);
  embed_kernel<<<dim3(48, S_LEN), 256, 0, stream>>>(tokens, Emb, Wx_swz, br, bz, bc, Xp);
  gru_kernel<<<256, 256, 0, stream>>>(Xp, Wr_swz, Wz_swz, Wc_swz,
                                      Hbf, Hf, rh, zscr, pscr, slots);
  logits_kernel<<<B_SZ, 64, 0, stream>>>(Hf, Whq, bq, (float*)d_out);
}

// Round 3
// 8474.780 us; speedup vs baseline: 2.3016x; 2.3016x over previous
//
#include <hip/hip_runtime.h>
#include <stdint.h>

// ---------------- problem constants ----------------
#define S_LEN 512
#define B_SZ  64
#define E_DIM 512
#define HD    1024
#define NGATE 3072   // 3*HD (r,z,c)
#define O_DIM 10

typedef __attribute__((ext_vector_type(4))) float f32x4;
typedef __attribute__((ext_vector_type(8))) short bf16x8;   // 8 bf16 in 4 VGPRs

__device__ __forceinline__ float bf2f(unsigned short u) {
  union { unsigned int i; float f; } c; c.i = ((unsigned int)u) << 16; return c.f;
}
__device__ __forceinline__ unsigned short f2bf(float f) {   // RNE
  union { float f; unsigned int i; } c; c.f = f;
  unsigned int u = c.i;
  return (unsigned short)((u + 0x7fffu + ((u >> 16) & 1u)) >> 16);
}
__device__ __forceinline__ float sigmoid_fast(float x) { return 1.0f / (1.0f + __expf(-x)); }
__device__ __forceinline__ float tanh_fast(float x) {
  float a = fabsf(x);
  float e = __expf(2.0f * a);
  return copysignf(1.0f - 2.0f / (e + 1.0f), x);
}
__device__ __forceinline__ f32x4 mfma16(bf16x8 a, bf16x8 b, f32x4 c) {
  return __builtin_amdgcn_mfma_f32_16x16x32_bf16(a, b, c, 0, 0, 0);
}
// agent-scope atomics: act at the cross-XCD coherent point (LLC).
__device__ __forceinline__ unsigned long long ld_u64_agent(const unsigned long long* p) {
  return __hip_atomic_load(p, __ATOMIC_RELAXED, __HIP_MEMORY_SCOPE_AGENT);
}
// payload writes as RMW exchange: RMW atomics are HW-verified (m20) to execute
// at the device coherent point -- guaranteed visible once vmcnt(0) retires.
__device__ __forceinline__ void xchg_u64_agent(unsigned long long* p, unsigned long long v) {
  (void)__hip_atomic_exchange(p, v, __ATOMIC_RELAXED, __HIP_MEMORY_SCOPE_AGENT);
}

// ---------------- ws layout (bytes) ----------------
#define OFF_HBF   0
#define OFF_HF    262144
#define OFF_SLOTS 524288
#define OFF_ZSCR  525312     // memset end
#define OFF_RH    1573888
#define OFF_WR    1704960
#define OFF_WZ    3802112
#define OFF_WC    5899264
#define OFF_WX    7996416
#define OFF_XP    11142144

// ============================================================================
// convert: fp32 weights -> bf16, pre-swizzled into MFMA B-fragment order.
// ============================================================================
__global__ void convert_kernel(const float* __restrict__ Whr, const float* __restrict__ Whz,
                               const float* __restrict__ Whc,
                               const float* __restrict__ Wxr, const float* __restrict__ Wxz,
                               const float* __restrict__ Wxc,
                               unsigned short* __restrict__ Wr_swz, unsigned short* __restrict__ Wz_swz,
                               unsigned short* __restrict__ Wc_swz, unsigned short* __restrict__ Wx_swz) {
  long idx = (long)blockIdx.x * blockDim.x + threadIdx.x;
  const long NH = (long)HD * HD;
  if (idx < 3 * NH) {
    int m = (int)(idx >> 20);
    int t = (int)(idx & (NH - 1));
    int k = t >> 10, j = t & 1023;
    const float* src = (m == 0) ? Whr : (m == 1) ? Whz : Whc;
    unsigned short* dst = (m == 0) ? Wr_swz : (m == 1) ? Wz_swz : Wc_swz;
    int jt = j >> 4, n = j & 15, kt = k >> 5, q = (k >> 3) & 3, i = k & 7;
    dst[((long)(jt * 32 + kt) * 64 + (q * 16 + n)) * 8 + i] = f2bf(src[(long)k * HD + j]);
  } else {
    long t = idx - 3 * NH;
    if (t < (long)E_DIM * NGATE) {
      int e  = (int)(t / NGATE);
      int jg = (int)(t - (long)e * NGATE);
      int jt = jg >> 4, n = jg & 15, kt = e >> 5, q = (e >> 3) & 3, i = e & 7;
      int gate = jg >> 10, jj = jg & 1023;
      const float* src = (gate == 0) ? Wxr : (gate == 1) ? Wxz : Wxc;
      Wx_swz[((long)(jt * 16 + kt) * 64 + (q * 16 + n)) * 8 + i] = f2bf(src[(long)e * HD + jj]);
    }
  }
}

// ============================================================================
// embed + X-projection: Xp[s][jglob][b] (bf16, bias folded in)
// ============================================================================
__launch_bounds__(256, 2)
__global__ void embed_kernel(const int* __restrict__ tokens,
                             const float* __restrict__ Emb,
                             const unsigned short* __restrict__ Wx_swz,
                             const float* __restrict__ b_r, const float* __restrict__ b_z,
                             const float* __restrict__ b_c,
                             unsigned short* __restrict__ Xp) {
  __shared__ unsigned short xl[B_SZ * E_DIM];   // 64 KB
  const int s = blockIdx.y;
  const int slab = blockIdx.x;                  // 0..47
  const int tid = threadIdx.x;
  for (int it = 0; it < 32; ++it) {
    int task = tid + 256 * it;
    int row = task >> 7;
    int f = task & 127;
    int tok = tokens[row * S_LEN + s];
    float4 v = *(const float4*)(Emb + (long)tok * E_DIM + f * 4);
    int sw = (f >> 1) ^ (row & 7);
    unsigned short* p = xl + row * E_DIM + sw * 8 + (f & 1) * 4;
    p[0] = f2bf(v.x); p[1] = f2bf(v.y); p[2] = f2bf(v.z); p[3] = f2bf(v.w);
  }
  __syncthreads();
  const int lane = tid & 63, wave = tid >> 6;
  const int n = lane & 15, q = lane >> 4;
  const int jt_glob = slab * 4 + wave;
  f32x4 acc[4];
  #pragma unroll
  for (int bt = 0; bt < 4; ++bt) { acc[bt][0]=0.f; acc[bt][1]=0.f; acc[bt][2]=0.f; acc[bt][3]=0.f; }
  for (int kt = 0; kt < 16; ++kt) {
    bf16x8 bfrag = *(const bf16x8*)(Wx_swz + ((long)(jt_glob * 16 + kt) * 64 + lane) * 8);
    #pragma unroll
    for (int bt = 0; bt < 4; ++bt) {
      int row = bt * 16 + n;
      int chunk = (kt * 4 + q) ^ (row & 7);
      bf16x8 afrag = *(const bf16x8*)(xl + row * E_DIM + chunk * 8);
      acc[bt] = mfma16(afrag, bfrag, acc[bt]);
    }
  }
  const int jglob = jt_glob * 16 + n;
  const int gate = jglob >> 10, jj = jglob & 1023;
  const float bias = (gate == 0 ? b_r : gate == 1 ? b_z : b_c)[jj];
  #pragma unroll
  for (int bt = 0; bt < 4; ++bt) {
    unsigned int lo = (unsigned)f2bf(acc[bt][0] + bias) | ((unsigned)f2bf(acc[bt][1] + bias) << 16);
    unsigned int hi = (unsigned)f2bf(acc[bt][2] + bias) | ((unsigned)f2bf(acc[bt][3] + bias) << 16);
    uint2 pk; pk.x = lo; pk.y = hi;
    *(uint2*)(Xp + ((long)s * NGATE + jglob) * B_SZ + bt * 16 + q * 4) = pk;
  }
}

// ============================================================================
// persistent GRU, fence-free message passing (R2 + two fixes):
//   FIX1: s_waitcnt lgkmcnt(0) + memory clobber between ldsT transpose write
//         and u64 readback (R2 let the compiler reorder the ds_read past the
//         ds_writes -- TBAA says short/u64 don't alias)
//   FIX2: payload stores are agent-scope atomic EXCHANGES -- RMW executes at
//         the device coherent point (m20-verified), so payload is globally
//         visible once vmcnt(0) retires, before the release flag store.
// ============================================================================
__launch_bounds__(256, 1)
__global__ void gru_kernel(const unsigned short* __restrict__ Xp,
                           const unsigned short* __restrict__ Wr_swz,
                           const unsigned short* __restrict__ Wz_swz,
                           const unsigned short* __restrict__ Wc_swz,
                           unsigned short* __restrict__ Hbf,    // [2][64][1024] bf16
                           float* __restrict__ Hf,              // [64][1024] fp32 (last step only)
                           unsigned short* __restrict__ rh,     // [64][1024] bf16 (r*H)
                           unsigned int* __restrict__ slots) {  // [4][64]
  __shared__ unsigned short wrz[2 * 32 * 64 * 8];               // 64 KB: Wr|Wz slices, frag order
  __shared__ float red[8][256];                                  // 8 KB cross-wave reduction
  __shared__ float zbuf[256];                                    // z stash (phase1 -> phase2)
  __shared__ unsigned short ldsT[256];                           // 16x16 bf16 transpose staging
  const int tid = threadIdx.x;
  const int lane = tid & 63, w = tid >> 6;
  const int n = lane & 15, q = lane >> 4;
  const int blk = blockIdx.x;
  const int g  = blk & 3;                       // batch group (rows 16g..16g+15)
  const int bh = blk >> 2;                      // j-tile owner, j in [16bh, 16bh+16)
  const int jmine = bh * 16 + n;

  { // one-time: W_r, W_z slices -> LDS (already in frag order, linear copy)
    const uint4* s0 = (const uint4*)(Wr_swz + (long)bh * (32 * 64 * 8));
    const uint4* s1 = (const uint4*)(Wz_swz + (long)bh * (32 * 64 * 8));
    uint4* d0 = (uint4*)wrz;
    uint4* d1 = (uint4*)(wrz + 32 * 64 * 8);
    for (int i = tid; i < 2048; i += 256) { d0[i] = s0[i]; d1[i] = s1[i]; }
  }
  __syncthreads();
  const unsigned short* WcB = Wc_swz + (long)bh * (32 * 64 * 8);
  unsigned int* slot_base = slots + g * 64;
  unsigned long long* rh_u64  = (unsigned long long*)rh;
  const int row_t = lane >> 2, word_t = lane & 3;  // transpose-store mapping

  int cur = 0;
  unsigned int seq = 1;
  f32x4 hold; hold[0]=0.f; hold[1]=0.f; hold[2]=0.f; hold[3]=0.f;  // wave0: fp32 H master

  for (int s = 0; s < S_LEN; ++s) {
    // ================= phase 1: r,z partials; each wave owns a unique K-quarter =================
    uint2 xp01; xp01.x = 0; xp01.y = 0;
    if (w < 2)   // wave0: Xp_r, wave1: Xp_z
      xp01 = *(const uint2*)(Xp + ((long)s * NGATE + w * HD + jmine) * B_SZ + g * 16 + q * 4);

    {
      const unsigned long long* Ab =
          (const unsigned long long*)(Hbf + (long)cur * (B_SZ * HD) + (long)(g * 16 + n) * HD + q * 8);
      unsigned long long a0[8], a1[8];
      #pragma unroll
      for (int t = 0; t < 8; ++t) {
        int kt = w * 8 + t;
        a0[t] = ld_u64_agent(Ab + kt * 8);
        a1[t] = ld_u64_agent(Ab + kt * 8 + 1);
      }
      f32x4 accR; accR[0]=0.f; accR[1]=0.f; accR[2]=0.f; accR[3]=0.f;
      f32x4 accZ = accR;
      #pragma unroll
      for (int t = 0; t < 8; ++t) {
        int kt = w * 8 + t;
        union { unsigned long long u[2]; bf16x8 v; } af;
        af.u[0] = a0[t]; af.u[1] = a1[t];
        bf16x8 br_ = *(const bf16x8*)(wrz + kt * 512 + lane * 8);
        bf16x8 bz_ = *(const bf16x8*)(wrz + 32 * 512 + kt * 512 + lane * 8);
        accR = mfma16(af.v, br_, accR);
        accZ = mfma16(af.v, bz_, accZ);
      }
      *(f32x4*)(&red[w][lane * 4])     = accR;
      *(f32x4*)(&red[4 + w][lane * 4]) = accZ;
    }
    __syncthreads();
    if (w == 0) {
      f32x4 acc = *(const f32x4*)(&red[0][lane * 4]);
      #pragma unroll
      for (int k = 1; k < 4; ++k) { f32x4 p = *(const f32x4*)(&red[k][lane * 4]); acc += p; }
      #pragma unroll
      for (int r_ = 0; r_ < 4; ++r_) {
        float xpv = bf2f((unsigned short)(((r_ < 2) ? xp01.x : xp01.y) >> ((r_ & 1) * 16)));
        float rv = sigmoid_fast(acc[r_] + xpv);
        ldsT[(q * 4 + r_) * 16 + n] = f2bf(rv * hold[r_]);     // rh tile, (row,col)
      }
      asm volatile("s_waitcnt lgkmcnt(0)" ::: "memory");        // FIX1: order ds_write -> ds_read
      unsigned long long pay = *(const unsigned long long*)(ldsT + row_t * 16 + word_t * 4);
      xchg_u64_agent(rh_u64 + (((long)(g * 16 + row_t) * HD + bh * 16 + word_t * 4) >> 2), pay);  // FIX2
      asm volatile("s_waitcnt vmcnt(0)" ::: "memory");          // payload at coherent point
      if (lane == 0)
        __hip_atomic_store(slot_base + bh, seq, __ATOMIC_RELEASE, __HIP_MEMORY_SCOPE_AGENT);
      unsigned int v;                                           // poll 64 flags, one per lane
      do {
        v = __hip_atomic_load(slot_base + lane, __ATOMIC_RELAXED, __HIP_MEMORY_SCOPE_AGENT);
        if (v >= seq) break;
        __builtin_amdgcn_s_sleep(2);
      } while (true);
    } else if (w == 1) {
      f32x4 acc = *(const f32x4*)(&red[4][lane * 4]);
      #pragma unroll
      for (int k = 5; k < 8; ++k) { f32x4 p = *(const f32x4*)(&red[k][lane * 4]); acc += p; }
      #pragma unroll
      for (int r_ = 0; r_ < 4; ++r_) {
        float xpv = bf2f((unsigned short)(((r_ < 2) ? xp01.x : xp01.y) >> ((r_ & 1) * 16)));
        zbuf[(q * 4 + r_) * 16 + n] = sigmoid_fast(acc[r_] + xpv);
      }
    }
    asm volatile("" ::: "memory");
    __syncthreads();
    seq++;

    // ================= phase 2: c tile (K-split 4 over waves), H update =================
    uint2 xpc; xpc.x = 0; xpc.y = 0;
    if (w == 0)
      xpc = *(const uint2*)(Xp + ((long)s * NGATE + 2 * HD + jmine) * B_SZ + g * 16 + q * 4);
    {
      const unsigned long long* Rb =
          (const unsigned long long*)(rh + (long)(g * 16 + n) * HD + q * 8);
      unsigned long long c0[8], c1[8];
      #pragma unroll
      for (int t = 0; t < 8; ++t) {
        int kt = w * 8 + t;
        c0[t] = ld_u64_agent(Rb + kt * 8);
        c1[t] = ld_u64_agent(Rb + kt * 8 + 1);
      }
      f32x4 acc2; acc2[0]=0.f; acc2[1]=0.f; acc2[2]=0.f; acc2[3]=0.f;
      #pragma unroll
      for (int t = 0; t < 8; ++t) {
        int kt = w * 8 + t;
        union { unsigned long long u[2]; bf16x8 v; } af;
        af.u[0] = c0[t]; af.u[1] = c1[t];
        bf16x8 bf_ = *(const bf16x8*)(WcB + (long)kt * 512 + lane * 8);  // plain load, L2-warm
        acc2 = mfma16(af.v, bf_, acc2);
      }
      *(f32x4*)(&red[w][lane * 4]) = acc2;
    }
    __syncthreads();
    if (w == 0) {
      f32x4 acc2 = *(const f32x4*)(&red[0][lane * 4]);
      #pragma unroll
      for (int k = 1; k < 4; ++k) { f32x4 p = *(const f32x4*)(&red[k][lane * 4]); acc2 += p; }
      unsigned long long* Hbn_u64 =
          (unsigned long long*)(Hbf + (long)(cur ^ 1) * (B_SZ * HD));
      #pragma unroll
      for (int r_ = 0; r_ < 4; ++r_) {
        float xpv = bf2f((unsigned short)(((r_ < 2) ? xpc.x : xpc.y) >> ((r_ & 1) * 16)));
        float c = tanh_fast(acc2[r_] + xpv);
        float z = zbuf[(q * 4 + r_) * 16 + n];
        float hn = z * hold[r_] + (1.0f - z) * c;
        hold[r_] = hn;
        ldsT[(q * 4 + r_) * 16 + n] = f2bf(hn);
        if (s == S_LEN - 1) Hf[(long)(g * 16 + q * 4 + r_) * HD + jmine] = hn;
      }
      asm volatile("s_waitcnt lgkmcnt(0)" ::: "memory");        // FIX1
      unsigned long long pay = *(const unsigned long long*)(ldsT + row_t * 16 + word_t * 4);
      xchg_u64_agent((unsigned long long*)(Hbf + (long)(cur ^ 1) * (B_SZ * HD)) +
                     (((long)(g * 16 + row_t) * HD + bh * 16 + word_t * 4) >> 2), pay);  // FIX2
      asm volatile("s_waitcnt vmcnt(0)" ::: "memory");
      if (lane == 0)
        __hip_atomic_store(slot_base + bh, seq, __ATOMIC_RELEASE, __HIP_MEMORY_SCOPE_AGENT);
      unsigned int v;
      do {
        v = __hip_atomic_load(slot_base + lane, __ATOMIC_RELAXED, __HIP_MEMORY_SCOPE_AGENT);
        if (v >= seq) break;
        __builtin_amdgcn_s_sleep(2);
      } while (true);
    }
    asm volatile("" ::: "memory");
    __syncthreads();
    seq++;
    cur ^= 1;
  }
}

// ============================================================================
// logits + softmax: one wave per batch row
// ============================================================================
__global__ void logits_kernel(const float* __restrict__ Hf, const float* __restrict__ Whq,
                              const float* __restrict__ bq, float* __restrict__ out) {
  const int b = blockIdx.x;
  const int lane = threadIdx.x;   // 64
  float acc[O_DIM];
  #pragma unroll
  for (int o = 0; o < O_DIM; ++o) acc[o] = 0.f;
  for (int k = lane; k < HD; k += 64) {
    float h = Hf[(long)b * HD + k];
    #pragma unroll
    for (int o = 0; o < O_DIM; ++o) acc[o] += h * Whq[(long)k * O_DIM + o];
  }
  #pragma unroll
  for (int o = 0; o < O_DIM; ++o) {
    #pragma unroll
    for (int off = 32; off > 0; off >>= 1) acc[o] += __shfl_down(acc[o], off, 64);
  }
  if (lane == 0) {
    float lg[O_DIM], m = -1e30f, sum = 0.f;
    #pragma unroll
    for (int o = 0; o < O_DIM; ++o) { lg[o] = acc[o] + bq[o]; m = fmaxf(m, lg[o]); }
    #pragma unroll
    for (int o = 0; o < O_DIM; ++o) { lg[o] = __expf(lg[o] - m); sum += lg[o]; }
    float inv = 1.0f / sum;
    #pragma unroll
    for (int o = 0; o < O_DIM; ++o) out[(long)b * O_DIM + o] = lg[o] * inv;
  }
}

// ============================================================================
extern "C" void kernel_launch(void* const* d_in, const int* in_sizes, int n_in,
                              void* d_out, int out_size, void* d_ws, size_t ws_size,
                              hipStream_t stream) {
  const int*   tokens = (const int*)d_in[0];
  const float* Emb = (const float*)d_in[1];
  const float* Wxr = (const float*)d_in[2];
  const float* Whr = (const float*)d_in[3];
  const float* br  = (const float*)d_in[4];
  const float* Wxz = (const float*)d_in[5];
  const float* Whz = (const float*)d_in[6];
  const float* bz  = (const float*)d_in[7];
  const float* Wxc = (const float*)d_in[8];
  const float* Whc = (const float*)d_in[9];
  const float* bc  = (const float*)d_in[10];
  const float* Whq = (const float*)d_in[11];
  const float* bq  = (const float*)d_in[12];

  char* ws = (char*)d_ws;
  unsigned short* Hbf    = (unsigned short*)(ws + OFF_HBF);
  float*          Hf     = (float*)(ws + OFF_HF);
  unsigned int*   slots  = (unsigned int*)(ws + OFF_SLOTS);
  unsigned short* rh     = (unsigned short*)(ws + OFF_RH);
  unsigned short* Wr_swz = (unsigned short*)(ws + OFF_WR);
  unsigned short* Wz_swz = (unsigned short*)(ws + OFF_WZ);
  unsigned short* Wc_swz = (unsigned short*)(ws + OFF_WC);
  unsigned short* Wx_swz = (unsigned short*)(ws + OFF_WX);
  unsigned short* Xp     = (unsigned short*)(ws + OFF_XP);

  // zero H0 (both bf16 H buffers) and barrier slots
  hipMemsetAsync(ws, 0, OFF_ZSCR, stream);

  convert_kernel<<<18432, 256, 0, stream>>>(Whr, Whz, Whc, Wxr, Wxz, Wxc,
                                            Wr_swz, Wz_swz, Wc_swz, Wx_swz);
  embed_kernel<<<dim3(48, S_LEN), 256, 0, stream>>>(tokens, Emb, Wx_swz, br, bz, bc, Xp);
  gru_kernel<<<256, 256, 0, stream>>>(Xp, Wr_swz, Wz_swz, Wc_swz,
                                      Hbf, Hf, rh, slots);
  logits_kernel<<<B_SZ, 64, 0, stream>>>(Hf, Whq, bq, (float*)d_out);
}

// Round 5
// 5364.841 us; speedup vs baseline: 3.6359x; 1.5797x over previous
//
#include <hip/hip_runtime.h>
#include <stdint.h>

// ---------------- problem constants ----------------
#define S_LEN 512
#define B_SZ  64
#define E_DIM 512
#define HD    1024
#define NGATE 3072   // 3*HD (r,z,c)
#define O_DIM 10

typedef __attribute__((ext_vector_type(4))) float f32x4;
typedef __attribute__((ext_vector_type(8))) short bf16x8;   // 8 bf16 in 4 VGPRs

__device__ __forceinline__ float bf2f(unsigned short u) {
  union { unsigned int i; float f; } c; c.i = ((unsigned int)u) << 16; return c.f;
}
__device__ __forceinline__ unsigned short f2bf(float f) {   // RNE
  union { float f; unsigned int i; } c; c.f = f;
  unsigned int u = c.i;
  return (unsigned short)((u + 0x7fffu + ((u >> 16) & 1u)) >> 16);
}
__device__ __forceinline__ float sigmoid_fast(float x) { return 1.0f / (1.0f + __expf(-x)); }
__device__ __forceinline__ float tanh_fast(float x) {
  float a = fabsf(x);
  float e = __expf(2.0f * a);
  return copysignf(1.0f - 2.0f / (e + 1.0f), x);
}
__device__ __forceinline__ f32x4 mfma16(bf16x8 a, bf16x8 b, f32x4 c) {
  return __builtin_amdgcn_mfma_f32_16x16x32_bf16(a, b, c, 0, 0, 0);
}
// ---- R3-proven device-coherent primitives (LLC message passing) ----
__device__ __forceinline__ unsigned long long ld_u64_agent(const unsigned long long* p) {
  return __hip_atomic_load(p, __ATOMIC_RELAXED, __HIP_MEMORY_SCOPE_AGENT);
}
__device__ __forceinline__ void xchg_u64_agent(unsigned long long* p, unsigned long long v) {
  (void)__hip_atomic_exchange(p, v, __ATOMIC_RELAXED, __HIP_MEMORY_SCOPE_AGENT);
}

// ---------------- ws layout (bytes) ----------------
#define OFF_HBF   0          // [2][64][1024] bf16 = 256 KB
#define OFF_HF    262144     // [64][1024] f32  = 256 KB
#define OFF_SLOTS 524288     // [4][32] u32
#define OFF_ZSCR  525312     // memset end
#define OFF_RH    1573888
#define OFF_WR    1704960
#define OFF_WZ    3802112
#define OFF_WC    5899264
#define OFF_WX    7996416
#define OFF_XP    11142144

// ============================================================================
// convert: fp32 weights -> bf16, pre-swizzled into MFMA B-fragment order.
// ============================================================================
__global__ void convert_kernel(const float* __restrict__ Whr, const float* __restrict__ Whz,
                               const float* __restrict__ Whc,
                               const float* __restrict__ Wxr, const float* __restrict__ Wxz,
                               const float* __restrict__ Wxc,
                               unsigned short* __restrict__ Wr_swz, unsigned short* __restrict__ Wz_swz,
                               unsigned short* __restrict__ Wc_swz, unsigned short* __restrict__ Wx_swz) {
  long idx = (long)blockIdx.x * blockDim.x + threadIdx.x;
  const long NH = (long)HD * HD;
  if (idx < 3 * NH) {
    int m = (int)(idx >> 20);
    int t = (int)(idx & (NH - 1));
    int k = t >> 10, j = t & 1023;
    const float* src = (m == 0) ? Whr : (m == 1) ? Whz : Whc;
    unsigned short* dst = (m == 0) ? Wr_swz : (m == 1) ? Wz_swz : Wc_swz;
    int jt = j >> 4, n = j & 15, kt = k >> 5, q = (k >> 3) & 3, i = k & 7;
    dst[((long)(jt * 32 + kt) * 64 + (q * 16 + n)) * 8 + i] = f2bf(src[(long)k * HD + j]);
  } else {
    long t = idx - 3 * NH;
    if (t < (long)E_DIM * NGATE) {
      int e  = (int)(t / NGATE);
      int jg = (int)(t - (long)e * NGATE);
      int jt = jg >> 4, n = jg & 15, kt = e >> 5, q = (e >> 3) & 3, i = e & 7;
      int gate = jg >> 10, jj = jg & 1023;
      const float* src = (gate == 0) ? Wxr : (gate == 1) ? Wxz : Wxc;
      Wx_swz[((long)(jt * 16 + kt) * 64 + (q * 16 + n)) * 8 + i] = f2bf(src[(long)e * HD + jj]);
    }
  }
}

// ============================================================================
// embed + X-projection -> Xp[s][g][jglob][16b] (bf16, bias folded in).
// Group-contiguous inner layout: each GRU group reads dense runs.
// ============================================================================
__launch_bounds__(256, 2)
__global__ void embed_kernel(const int* __restrict__ tokens,
                             const float* __restrict__ Emb,
                             const unsigned short* __restrict__ Wx_swz,
                             const float* __restrict__ b_r, const float* __restrict__ b_z,
                             const float* __restrict__ b_c,
                             unsigned short* __restrict__ Xp) {
  __shared__ unsigned short xl[B_SZ * E_DIM];   // 64 KB
  const int s = blockIdx.y;
  const int slab = blockIdx.x;                  // 0..47
  const int tid = threadIdx.x;
  for (int it = 0; it < 32; ++it) {
    int task = tid + 256 * it;
    int row = task >> 7;
    int f = task & 127;
    int tok = tokens[row * S_LEN + s];
    float4 v = *(const float4*)(Emb + (long)tok * E_DIM + f * 4);
    int sw = (f >> 1) ^ (row & 7);
    unsigned short* p = xl + row * E_DIM + sw * 8 + (f & 1) * 4;
    p[0] = f2bf(v.x); p[1] = f2bf(v.y); p[2] = f2bf(v.z); p[3] = f2bf(v.w);
  }
  __syncthreads();
  const int lane = tid & 63, wave = tid >> 6;
  const int n = lane & 15, q = lane >> 4;
  const int jt_glob = slab * 4 + wave;
  f32x4 acc[4];
  #pragma unroll
  for (int bt = 0; bt < 4; ++bt) { acc[bt][0]=0.f; acc[bt][1]=0.f; acc[bt][2]=0.f; acc[bt][3]=0.f; }
  for (int kt = 0; kt < 16; ++kt) {
    bf16x8 bfrag = *(const bf16x8*)(Wx_swz + ((long)(jt_glob * 16 + kt) * 64 + lane) * 8);
    #pragma unroll
    for (int bt = 0; bt < 4; ++bt) {
      int row = bt * 16 + n;
      int chunk = (kt * 4 + q) ^ (row & 7);
      bf16x8 afrag = *(const bf16x8*)(xl + row * E_DIM + chunk * 8);
      acc[bt] = mfma16(afrag, bfrag, acc[bt]);
    }
  }
  const int jglob = jt_glob * 16 + n;
  const int gate = jglob >> 10, jj = jglob & 1023;
  const float bias = (gate == 0 ? b_r : gate == 1 ? b_z : b_c)[jj];
  #pragma unroll
  for (int bt = 0; bt < 4; ++bt) {              // bt == batch group
    unsigned int lo = (unsigned)f2bf(acc[bt][0] + bias) | ((unsigned)f2bf(acc[bt][1] + bias) << 16);
    unsigned int hi = (unsigned)f2bf(acc[bt][2] + bias) | ((unsigned)f2bf(acc[bt][3] + bias) << 16);
    uint2 pk; pk.x = lo; pk.y = hi;             // rows 4q..4q+3 within group
    *(uint2*)(Xp + (((long)s * 4 + bt) * NGATE + jglob) * 16 + q * 4) = pk;
  }
}

// ============================================================================
// persistent GRU, R3-proven LLC protocol + three structural changes:
//   - 128 blocks: 4 groups x 32 blocks (fan-in halved vs R3; all resident
//     regardless of scheduling -- no placement assumptions, G16-safe)
//   - ALL weights (Wr,Wz,Wc slices) held in REGISTERS: 48 bf16x8/lane.
//     Zero per-step weight traffic, zero LDS B-reads. LDS = 21 KB.
//   - Xp prefetched one step ahead into registers (HBM off critical path)
// Per phase: agent-load A (H or rh) -> MFMA (B from regs) -> LDS reduce ->
// gate math -> xchg payload -> vmcnt(0) -> sync -> flag -> poll -> sync.
// ============================================================================
__launch_bounds__(256, 1)
__global__ void gru_kernel(const unsigned short* __restrict__ Xp,
                           const unsigned short* __restrict__ Wr_swz,
                           const unsigned short* __restrict__ Wz_swz,
                           const unsigned short* __restrict__ Wc_swz,
                           unsigned short* __restrict__ Hbf,    // [2][64][1024] bf16
                           float* __restrict__ Hf,              // [64][1024] f32 (last step)
                           unsigned short* __restrict__ rh,     // [64][1024] bf16
                           unsigned int* __restrict__ slots) {  // [4][32]
  __shared__ float red[4][4][256];              // 16 KB [src wave][tile][...]
  __shared__ float zbuf[2][256];                // 2 KB
  __shared__ unsigned short ldsT[2][256];       // 1 KB transpose staging
  __shared__ float hmaster[16 * 32];            // 2 KB fp32 H master [row][col]

  const int tid = threadIdx.x;
  const int lane = tid & 63, w = tid >> 6;
  const int n = lane & 15, q = lane >> 4;
  const int blk = blockIdx.x;                   // 0..127
  const int g  = blk & 3;                       // batch group (rows 16g..16g+15)
  const int bh = blk >> 2;                      // j-slice [32bh, 32bh+32), bh 0..31
  const int row_t = lane >> 2, word_t = lane & 3;

  // ---- weights -> registers: per-wave K-quarter (kt = w*8..w*8+7), 2 j-tiles ----
  bf16x8 wr_reg[2][8], wz_reg[2][8], wc_reg[2][8];   // 192 VGPRs
  #pragma unroll
  for (int jt = 0; jt < 2; ++jt)
    #pragma unroll
    for (int t = 0; t < 8; ++t) {
      long o = ((long)((2 * bh + jt) * 32 + w * 8 + t)) * 512 + lane * 8;
      wr_reg[jt][t] = *(const bf16x8*)(Wr_swz + o);
      wz_reg[jt][t] = *(const bf16x8*)(Wz_swz + o);
      wc_reg[jt][t] = *(const bf16x8*)(Wc_swz + o);
    }
  for (int i = tid; i < 512; i += 256) hmaster[i] = 0.f;   // H0 = 0
  __syncthreads();

  unsigned int* slot_base = slots + g * 32;
  unsigned long long* rh_u64 = (unsigned long long*)rh;

  // Xp pointers: wave w's phase-1 tile = (gate w>>1, jt w&1); waves 0,1 also c-tile w
  const int gate_w = w >> 1, jt_w = w & 1;
  const long xp_stride = (long)4 * NGATE * 16;   // shorts per step
  const unsigned short* xp1_p = Xp + (((long)g * NGATE) + gate_w * HD + bh * 32 + jt_w * 16 + n) * 16 + q * 4;
  const unsigned short* xpc_p = Xp + (((long)g * NGATE) + 2 * HD + bh * 32 + w * 16 + n) * 16 + q * 4;

  uint2 xp1 = *(const uint2*)xp1_p;              // step 0
  uint2 xpc; xpc.x = 0; xpc.y = 0;
  if (w < 2) xpc = *(const uint2*)xpc_p;

  int cur = 0;
  unsigned int seq = 1;

  for (int s = 0; s < S_LEN; ++s) {
    const long s_next = (s < S_LEN - 1) ? (long)(s + 1) : (long)s;
    // ============ phase 1: r,z (4 tiles), K-quarter per wave ============
    {
      const unsigned long long* Ab =
          (const unsigned long long*)(Hbf + (long)cur * (B_SZ * HD) + (long)(g * 16 + n) * HD + q * 8);
      unsigned long long a0[8], a1[8];
      #pragma unroll
      for (int t = 0; t < 8; ++t) {
        int kt = w * 8 + t;
        a0[t] = ld_u64_agent(Ab + kt * 8);
        a1[t] = ld_u64_agent(Ab + kt * 8 + 1);
      }
      // prefetch next step's Xp while A-loads are in flight
      uint2 xp1n = *(const uint2*)(xp1_p + s_next * xp_stride);
      uint2 xpcn; xpcn.x = 0; xpcn.y = 0;
      if (w < 2) xpcn = *(const uint2*)(xpc_p + s_next * xp_stride);

      f32x4 aR0, aR1, aZ0, aZ1;
      aR0[0]=0.f;aR0[1]=0.f;aR0[2]=0.f;aR0[3]=0.f; aR1=aR0; aZ0=aR0; aZ1=aR0;
      #pragma unroll
      for (int t = 0; t < 8; ++t) {
        union { unsigned long long u[2]; bf16x8 v; } af;
        af.u[0] = a0[t]; af.u[1] = a1[t];
        aR0 = mfma16(af.v, wr_reg[0][t], aR0);
        aR1 = mfma16(af.v, wr_reg[1][t], aR1);
        aZ0 = mfma16(af.v, wz_reg[0][t], aZ0);
        aZ1 = mfma16(af.v, wz_reg[1][t], aZ1);
      }
      *(f32x4*)&red[w][0][lane * 4] = aR0;
      *(f32x4*)&red[w][1][lane * 4] = aR1;
      *(f32x4*)&red[w][2][lane * 4] = aZ0;
      *(f32x4*)&red[w][3][lane * 4] = aZ1;
      __syncthreads();
      // wave t reduces tile t; tile == wave's own xp1 tile by construction
      f32x4 acc = *(const f32x4*)&red[0][w][lane * 4];
      #pragma unroll
      for (int k = 1; k < 4; ++k) { f32x4 p = *(const f32x4*)&red[k][w][lane * 4]; acc += p; }
      if (w < 2) {            // r tiles: rh = sigmoid(.)*H -> transpose -> LLC
        #pragma unroll
        for (int r_ = 0; r_ < 4; ++r_) {
          float xpv = bf2f((unsigned short)(((r_ < 2) ? xp1.x : xp1.y) >> ((r_ & 1) * 16)));
          float rv = sigmoid_fast(acc[r_] + xpv);
          ldsT[w][(q * 4 + r_) * 16 + n] = f2bf(rv * hmaster[(q * 4 + r_) * 32 + w * 16 + n]);
        }
        asm volatile("s_waitcnt lgkmcnt(0)" ::: "memory");
        unsigned long long pay = *(const unsigned long long*)(&ldsT[w][row_t * 16 + word_t * 4]);
        xchg_u64_agent(rh_u64 + (((long)(g * 16 + row_t) * HD + bh * 32 + w * 16 + word_t * 4) >> 2), pay);
        asm volatile("s_waitcnt vmcnt(0)" ::: "memory");
      } else {                // z tiles -> zbuf
        #pragma unroll
        for (int r_ = 0; r_ < 4; ++r_) {
          float xpv = bf2f((unsigned short)(((r_ < 2) ? xp1.x : xp1.y) >> ((r_ & 1) * 16)));
          zbuf[w - 2][(q * 4 + r_) * 16 + n] = sigmoid_fast(acc[r_] + xpv);
        }
      }
      xp1 = xp1n;
      if (w < 2) { /* keep xpcn for phase2 of NEXT step after current xpc used */ }
      __syncthreads();        // all payload stores retired (vmcnt drained per wave)
      if (tid == 0)
        __hip_atomic_store(slot_base + bh, seq, __ATOMIC_RELEASE, __HIP_MEMORY_SCOPE_AGENT);
      if (w == 0 && lane < 32) {
        unsigned int v;
        do {
          v = __hip_atomic_load(slot_base + lane, __ATOMIC_RELAXED, __HIP_MEMORY_SCOPE_AGENT);
          if (v >= seq) break;
          __builtin_amdgcn_s_sleep(1);
        } while (true);
      }
      __syncthreads();
      seq++;

      // ============ phase 2: c (2 tiles), K-quarter per wave ============
      const unsigned long long* Rb =
          (const unsigned long long*)(rh + (long)(g * 16 + n) * HD + q * 8);
      unsigned long long c0[8], c1[8];
      #pragma unroll
      for (int t = 0; t < 8; ++t) {
        int kt = w * 8 + t;
        c0[t] = ld_u64_agent(Rb + kt * 8);
        c1[t] = ld_u64_agent(Rb + kt * 8 + 1);
      }
      f32x4 cA, cB;
      cA[0]=0.f;cA[1]=0.f;cA[2]=0.f;cA[3]=0.f; cB = cA;
      #pragma unroll
      for (int t = 0; t < 8; ++t) {
        union { unsigned long long u[2]; bf16x8 v; } af;
        af.u[0] = c0[t]; af.u[1] = c1[t];
        cA = mfma16(af.v, wc_reg[0][t], cA);
        cB = mfma16(af.v, wc_reg[1][t], cB);
      }
      *(f32x4*)&red[w][0][lane * 4] = cA;
      *(f32x4*)&red[w][1][lane * 4] = cB;
      __syncthreads();
      if (w < 2) {            // wave w reduces c-tile w, updates H
        f32x4 acc2 = *(const f32x4*)&red[0][w][lane * 4];
        #pragma unroll
        for (int k = 1; k < 4; ++k) { f32x4 p = *(const f32x4*)&red[k][w][lane * 4]; acc2 += p; }
        #pragma unroll
        for (int r_ = 0; r_ < 4; ++r_) {
          float xpv = bf2f((unsigned short)(((r_ < 2) ? xpc.x : xpc.y) >> ((r_ & 1) * 16)));
          float cv = tanh_fast(acc2[r_] + xpv);
          float z  = zbuf[w][(q * 4 + r_) * 16 + n];
          float h0 = hmaster[(q * 4 + r_) * 32 + w * 16 + n];
          float hn = z * h0 + (1.0f - z) * cv;
          hmaster[(q * 4 + r_) * 32 + w * 16 + n] = hn;
          ldsT[w][(q * 4 + r_) * 16 + n] = f2bf(hn);
          if (s == S_LEN - 1)
            Hf[(long)(g * 16 + q * 4 + r_) * HD + bh * 32 + w * 16 + n] = hn;
        }
        asm volatile("s_waitcnt lgkmcnt(0)" ::: "memory");
        unsigned long long pay = *(const unsigned long long*)(&ldsT[w][row_t * 16 + word_t * 4]);
        xchg_u64_agent((unsigned long long*)(Hbf + (long)(cur ^ 1) * (B_SZ * HD)) +
                       (((long)(g * 16 + row_t) * HD + bh * 32 + w * 16 + word_t * 4) >> 2), pay);
        asm volatile("s_waitcnt vmcnt(0)" ::: "memory");
        xpc = xpcn;           // advance c-tile prefetch
      }
      __syncthreads();
      if (tid == 0)
        __hip_atomic_store(slot_base + bh, seq, __ATOMIC_RELEASE, __HIP_MEMORY_SCOPE_AGENT);
      if (w == 0 && lane < 32) {
        unsigned int v;
        do {
          v = __hip_atomic_load(slot_base + lane, __ATOMIC_RELAXED, __HIP_MEMORY_SCOPE_AGENT);
          if (v >= seq) break;
          __builtin_amdgcn_s_sleep(1);
        } while (true);
      }
      __syncthreads();
      seq++;
      cur ^= 1;
    }
  }
}

// ============================================================================
// logits + softmax: one wave per batch row
// ============================================================================
__global__ void logits_kernel(const float* __restrict__ Hf, const float* __restrict__ Whq,
                              const float* __restrict__ bq, float* __restrict__ out) {
  const int b = blockIdx.x;
  const int lane = threadIdx.x;   // 64
  float acc[O_DIM];
  #pragma unroll
  for (int o = 0; o < O_DIM; ++o) acc[o] = 0.f;
  for (int k = lane; k < HD; k += 64) {
    float h = Hf[(long)b * HD + k];
    #pragma unroll
    for (int o = 0; o < O_DIM; ++o) acc[o] += h * Whq[(long)k * O_DIM + o];
  }
  #pragma unroll
  for (int o = 0; o < O_DIM; ++o) {
    #pragma unroll
    for (int off = 32; off > 0; off >>= 1) acc[o] += __shfl_down(acc[o], off, 64);
  }
  if (lane == 0) {
    float lg[O_DIM], m = -1e30f, sum = 0.f;
    #pragma unroll
    for (int o = 0; o < O_DIM; ++o) { lg[o] = acc[o] + bq[o]; m = fmaxf(m, lg[o]); }
    #pragma unroll
    for (int o = 0; o < O_DIM; ++o) { lg[o] = __expf(lg[o] - m); sum += lg[o]; }
    float inv = 1.0f / sum;
    #pragma unroll
    for (int o = 0; o < O_DIM; ++o) out[(long)b * O_DIM + o] = lg[o] * inv;
  }
}

// ============================================================================
extern "C" void kernel_launch(void* const* d_in, const int* in_sizes, int n_in,
                              void* d_out, int out_size, void* d_ws, size_t ws_size,
                              hipStream_t stream) {
  const int*   tokens = (const int*)d_in[0];
  const float* Emb = (const float*)d_in[1];
  const float* Wxr = (const float*)d_in[2];
  const float* Whr = (const float*)d_in[3];
  const float* br  = (const float*)d_in[4];
  const float* Wxz = (const float*)d_in[5];
  const float* Whz = (const float*)d_in[6];
  const float* bz  = (const float*)d_in[7];
  const float* Wxc = (const float*)d_in[8];
  const float* Whc = (const float*)d_in[9];
  const float* bc  = (const float*)d_in[10];
  const float* Whq = (const float*)d_in[11];
  const float* bq  = (const float*)d_in[12];

  char* ws = (char*)d_ws;
  unsigned short* Hbf    = (unsigned short*)(ws + OFF_HBF);
  float*          Hf     = (float*)(ws + OFF_HF);
  unsigned int*   slots  = (unsigned int*)(ws + OFF_SLOTS);
  unsigned short* rh     = (unsigned short*)(ws + OFF_RH);
  unsigned short* Wr_swz = (unsigned short*)(ws + OFF_WR);
  unsigned short* Wz_swz = (unsigned short*)(ws + OFF_WZ);
  unsigned short* Wc_swz = (unsigned short*)(ws + OFF_WC);
  unsigned short* Wx_swz = (unsigned short*)(ws + OFF_WX);
  unsigned short* Xp     = (unsigned short*)(ws + OFF_XP);

  // zero H0 (both bf16 H buffers) and barrier slots
  hipMemsetAsync(ws, 0, OFF_ZSCR, stream);

  convert_kernel<<<18432, 256, 0, stream>>>(Whr, Whz, Whc, Wxr, Wxz, Wxc,
                                            Wr_swz, Wz_swz, Wc_swz, Wx_swz);
  embed_kernel<<<dim3(48, S_LEN), 256, 0, stream>>>(tokens, Emb, Wx_swz, br, bz, bc, Xp);
  gru_kernel<<<128, 256, 0, stream>>>(Xp, Wr_swz, Wz_swz, Wc_swz,
                                      Hbf, Hf, rh, slots);
  logits_kernel<<<B_SZ, 64, 0, stream>>>(Hf, Whq, bq, (float*)d_out);
}